// Round 1
// 168.478 us; speedup vs baseline: 1.0833x; 1.0833x over previous
//
#include <hip/hip_runtime.h>
#include <math.h>

typedef float f32x4 __attribute__((ext_vector_type(4)));

// RBF constants: means = linspace(exp(-5), 1, 128); beta = (2/128*(1-exp(-5)))^-2
#define RBF_START 0.006737946999085467f
#define RBF_H     (0.993262053000915f / 127.0f)
#define RBF_INVH  (127.0f / 0.993262053000915f)
#define RBF_BETA  (1.0f / ((2.0f/128.0f*0.993262053000915f) * (2.0f/128.0f*0.993262053000915f)))
#define KN 256          // knots: KN+1 samples of e in [0,1]; lerp err ~1e-6 on bias

// ---------------- kernel A: padding mask (blocks 0..2047) + bias-table build (blocks 2048..2304) ----------------
// Table: T[h][knot] = bias_h(e_knot), e_knot = knot/KN. Full f32, exact-erf GELU.
__global__ __launch_bounds__(256) void prep_kernel(
    const float* __restrict__ nf, int* __restrict__ mask,
    const float* __restrict__ w1, const float* __restrict__ b1,
    const float* __restrict__ w2, const float* __restrict__ b2,
    float* __restrict__ tableG) {
  int g = blockIdx.x, t = threadIdx.x;
  if (g < 2048) {
    const float* p = nf + (size_t)g * 768;
    bool nz = (p[t] != 0.f) || (p[t + 256] != 0.f) || (p[t + 512] != 0.f);
    __shared__ int wany[4];
    unsigned long long bal = __ballot(nz);
    if ((t & 63) == 0) wany[t >> 6] = (bal != 0ull);
    __syncthreads();
    if (t == 0) mask[g] = (wany[0] | wany[1] | wany[2] | wany[3]) ? 0 : 1;
  } else {
    int knot = g - 2048;                       // 0..256
    float e = (float)knot * (1.0f / (float)KN);
    __shared__ float ef_s[128];
    __shared__ float hid_s[128];
    if (t < 128) {
      float mu = fmaf((float)t, RBF_H, RBF_START);
      float diff = e - mu;
      ef_s[t] = __expf(-RBF_BETA * diff * diff);
    }
    __syncthreads();
    if (t < 128) {
      float s = b1[t];
      for (int k = 0; k < 128; k++) s = fmaf(ef_s[k], w1[k * 128 + t], s);
      hid_s[t] = 0.5f * s * (1.0f + erff(s * 0.70710678118654752f));  // exact GELU
    }
    __syncthreads();
    int h = t >> 3, seg = t & 7;               // 32 heads x 8 segments
    float s = 0.f;
    const float* hp = hid_s + seg * 16;
    const float* wp = w2 + (seg * 16) * 32 + h;
#pragma unroll
    for (int m = 0; m < 16; m++) s = fmaf(hp[m], wp[m * 32], s);
    s += __shfl_xor(s, 1);
    s += __shfl_xor(s, 2);
    s += __shfl_xor(s, 4);
    if (seg == 0) tableG[h * (KN + 1) + knot] = s + b2[h];
  }
}

// ---------------- kernel B: per-pair e -> 32 table lerps + banded column sums ----------------
// Block = 256 thr = one (b,i); thread t <-> key node j. LDS = 33.4 KB -> 4 blocks/CU.
__global__ __launch_bounds__(256, 4) void main_kernel(
    const float* __restrict__ pos, const int* __restrict__ mask,
    const float* __restrict__ tableG,
    float* __restrict__ out0, float* __restrict__ out2,
    float* __restrict__ part) {
  __shared__ float T_s[32 * (KN + 1)];     // 8224 f32 = 32896 B
  __shared__ float part_s[128];

  int t = threadIdx.x, g = blockIdx.x;
  int b = g >> 8, i = g & 255;

  // stage 0: table -> LDS (L2-hot, 33 KB), zero part accumulator
  {
    const f32x4* src = (const f32x4*)tableG;
    f32x4* dst = (f32x4*)T_s;
#pragma unroll
    for (int r = 0; r < 8; r++) dst[r * 256 + t] = src[r * 256 + t];
    if (t < 8) dst[2048 + t] = src[2048 + t];
  }
  if (t < 128) part_s[t] = 0.f;
  __syncthreads();

  // stage 1: distance, e = exp(-d), delta_pos out
  int j = t;
  const float* pb = pos + b * 768;
  float pix = pb[i * 3 + 0], piy = pb[i * 3 + 1], piz = pb[i * 3 + 2];
  float dx = pix - pb[j * 3 + 0];
  float dy = piy - pb[j * 3 + 1];
  float dz = piz - pb[j * 3 + 2];
  float r2 = dx * dx + dy * dy + dz * dz;
  float d = (r2 > 0.f) ? sqrtf(r2) : 0.f;
  float e = __expf(-d);                        // ALPHA=1, CUT_LO=0
  size_t base2 = ((size_t)g * 256 + (size_t)j) * 3;
  out2[base2 + 0] = dx; out2[base2 + 1] = dy; out2[base2 + 2] = dz;

  bool pad = mask[b * 256 + j] != 0;

  // stage 2: banded RBF -> LDS atomic column sums (exact exp path for part)
  if (!pad) {
    int kc = (int)rintf((e - RBF_START) * RBF_INVH);
    kc = min(max(kc, 0), 127);
    int kb = kc - 8;                           // exp(-beta*dk^2) < 8e-8 for |dk| >= 8
#pragma unroll
    for (int o = 0; o < 16; o++) {
      int k = kb + o;
      if (k >= 0 && k < 128) {
        float mu = fmaf((float)k, RBF_H, RBF_START);
        float diff = e - mu;
        atomicAdd(&part_s[k], __expf(-RBF_BETA * diff * diff));
      }
    }
  }

  // stage 3: 32-head bias via table lerp; coalesced 256B stores per head
  size_t ob = (size_t)b * 2097152 + (size_t)i * 256 + (size_t)j;
  if (pad) {
#pragma unroll
    for (int h = 0; h < 32; h++) out0[ob + (size_t)h * 65536] = -1e20f;
  } else {
    float u = e * (float)KN;
    int i0 = (int)u; i0 = min(i0, KN - 1);
    float fr = u - (float)i0;
#pragma unroll
    for (int h = 0; h < 32; h++) {
      float lo = T_s[h * (KN + 1) + i0];
      float hi = T_s[h * (KN + 1) + i0 + 1];
      out0[ob + (size_t)h * 65536] = fmaf(fr, hi - lo, lo);
    }
  }

  __syncthreads();
  if (t < 128) part[(size_t)g * 128 + t] = part_s[t];
}

// ---------------- kernel C: merge_edge_features = part @ ew + eb ----------------
__global__ __launch_bounds__(256) void merge_kernel(const float* __restrict__ part,
                                                    const float* __restrict__ ew,
                                                    const float* __restrict__ eb,
                                                    float* __restrict__ out1) {
  __shared__ float s_s[8][128];
  int t = threadIdx.x;
  int r0 = blockIdx.x * 8;
  for (int idx = t; idx < 1024; idx += 256) {
    int row = idx >> 7, k = idx & 127;
    s_s[row][k] = part[(size_t)(r0 + row) * 128 + k];
  }
  __syncthreads();
  float acc[3][8];
#pragma unroll
  for (int c = 0; c < 3; c++)
#pragma unroll
    for (int r = 0; r < 8; r++) acc[c][r] = 0.f;
  for (int k = 0; k < 128; k++) {
    float w0 = ew[k * 768 + t];
    float w1v = ew[k * 768 + t + 256];
    float w2v = ew[k * 768 + t + 512];
#pragma unroll
    for (int r = 0; r < 8; r++) {
      float s = s_s[r][k];
      acc[0][r] += s * w0;
      acc[1][r] += s * w1v;
      acc[2][r] += s * w2v;
    }
  }
#pragma unroll
  for (int c = 0; c < 3; c++) {
    float ebv = eb[c * 256 + t];
#pragma unroll
    for (int r = 0; r < 8; r++)
      out1[(size_t)(r0 + r) * 768 + c * 256 + t] = acc[c][r] + ebv;
  }
}

// ---------------- launch ----------------
extern "C" void kernel_launch(void* const* d_in, const int* in_sizes, int n_in,
                              void* d_out, int out_size, void* d_ws, size_t ws_size,
                              hipStream_t stream) {
    const float* nf    = (const float*)d_in[0];
    const float* pos   = (const float*)d_in[1];
    const float* w1    = (const float*)d_in[4];
    const float* b1    = (const float*)d_in[5];
    const float* w2    = (const float*)d_in[6];
    const float* b2    = (const float*)d_in[7];
    const float* ew    = (const float*)d_in[8];
    const float* eb    = (const float*)d_in[9];

    float* out0 = (float*)d_out;                         // [8,32,256,256]
    float* out1 = out0 + (size_t)8 * 32 * 256 * 256;     // [8,256,768]
    float* out2 = out1 + (size_t)8 * 256 * 768;          // [8,256,256,3]

    char* ws = (char*)d_ws;
    int*    mask   = (int*)ws;                           // 8 KB
    float*  tableG = (float*)(ws + 8192);                // 32896 B
    float*  part   = (float*)(ws + 49152);               // 2048*128*4 = 1 MB

    hipLaunchKernelGGL(prep_kernel,  dim3(2305), dim3(256), 0, stream,
                       nf, mask, w1, b1, w2, b2, tableG);
    hipLaunchKernelGGL(main_kernel,  dim3(2048), dim3(256), 0, stream,
                       pos, mask, tableG, out0, out2, part);
    hipLaunchKernelGGL(merge_kernel, dim3(256),  dim3(256), 0, stream, part, ew, eb, out1);
}